// Round 1
// baseline (105.002 us; speedup 1.0000x reference)
//
#include <hip/hip_runtime.h>
#include <hip/hip_bf16.h>

#define N_ROWS 8192
#define D_DIM  256

// loss_i = log(sum_{j != i} exp(<x_i,y_j>/T)) - <x_i,y_i>/T ; out = mean_i loss_i
// fp8 e4m3 inputs (scale 64), PLAIN row-major; acc = 4096*<x,y> via MX-scaled
// MFMA 16x16x128 with unit E8M0 scales (exact fp8 dot); 1/4096 in constants.
static constexpr float kQuantScale = 64.0f;
static constexpr float kScaleAcc = 20.609929155556627f / 4096.0f;  // (1/T)*log2(e)/4096
static constexpr float kInvTAcc  = 14.285714285714286f / 4096.0f;  // (1/T)/4096

typedef float f32x4 __attribute__((ext_vector_type(4)));
typedef int   i32x4 __attribute__((ext_vector_type(4)));
typedef int   i32x8 __attribute__((ext_vector_type(8)));

// async 16B global->LDS: LDS dest = wave-uniform base + lane*16
__device__ __forceinline__ void gl_lds16(const void* g, void* l) {
  __builtin_amdgcn_global_load_lds(
      (const __attribute__((address_space(1))) void*)g,
      (__attribute__((address_space(3))) void*)l, 16, 0, 0);
}

// ---------------- fp32 -> fp8 e4m3 pre-convert (plain layout) + ws init --------
__global__ __launch_bounds__(256)
void cvt_fp8_kernel(const float* __restrict__ x, const float* __restrict__ y,
                    unsigned char* __restrict__ xq, unsigned char* __restrict__ yq,
                    float* __restrict__ rowsum, unsigned int* __restrict__ done,
                    float* __restrict__ out) {
  if (blockIdx.x == 0) {
    for (int i = threadIdx.x; i < N_ROWS; i += 256) rowsum[i] = 0.f;
    if (threadIdx.x < 32) done[threadIdx.x] = 0u;
    if (threadIdx.x == 32) out[0] = 0.f;
  }
  const int per_mat = N_ROWS * D_DIM / 8;  // 8 elements per thread
  int idx = blockIdx.x * blockDim.x + threadIdx.x;
  const float* src = x;
  unsigned char* dst = xq;
  int i = idx;
  if (idx >= per_mat) { src = y; dst = yq; i = idx - per_mat; }
  float4 a = ((const float4*)src)[2 * (size_t)i];
  float4 b = ((const float4*)src)[2 * (size_t)i + 1];
  int v0 = 0, v1 = 0;
  v0 = __builtin_amdgcn_cvt_pk_fp8_f32(a.x * kQuantScale, a.y * kQuantScale, v0, false);
  v0 = __builtin_amdgcn_cvt_pk_fp8_f32(a.z * kQuantScale, a.w * kQuantScale, v0, true);
  v1 = __builtin_amdgcn_cvt_pk_fp8_f32(b.x * kQuantScale, b.y * kQuantScale, v1, false);
  v1 = __builtin_amdgcn_cvt_pk_fp8_f32(b.z * kQuantScale, b.w * kQuantScale, v1, true);
  *(int2*)(dst + (size_t)i * 8) = make_int2(v0, v1);   // plain row-major
}

// ---------------- persistent fused GEMM(MX-fp8) + exp + row-sum + finalize -----
// R15 chassis: 256 persistent blocks (1/CU), 512 threads = 8 waves (wm 0..3,
// wn 0..1). X-block (256 rows, full K) staged once (64 KB); Y: 8 tiles of 128
// cols full-K double-buffered (64 KB). 8 rounds, one barrier per tile.
// R17: row-sum partials in 16 registers (psum), one reduce+flush per block.
// R18 CHANGES:
//  (a) X fragments hoisted to REGISTERS (a8r[2][4], 64 VGPR), loaded from LDS
//      once in the prologue — X is block-invariant across rounds, so the 16
//      per-round A ds_read_b128 (half of all LDS traffic, 128 KB/CU/round)
//      and their lgkm dependency are removed from the round critical path.
//  (b) finalize distributed per bi-group: the 8 blocks sharing bi ticket on
//      done[bi]; the 8th finalizes its own 256 rows and atomicAdds the
//      partial loss into out (zeroed by cvt). 32 concurrent finalizes replace
//      the serial 1-block 8192-row tail. Same fence/ticket memory-model
//      pattern as the R12-validated global version.
__global__ __launch_bounds__(512, 1)
void infonce_gemm(const unsigned char* __restrict__ X,
                  const unsigned char* __restrict__ Y,
                  float* __restrict__ rowsum, float* __restrict__ diag,
                  unsigned int* __restrict__ done, float* __restrict__ out) {
  __shared__ unsigned char Xs[256 * 256];      // 64 KB, X-block full-K (prologue only)
  __shared__ unsigned char Ys[2][128 * 256];   // 2 x 32 KB, Y tile dbuf
  __shared__ unsigned int ticket_s;

  const int b  = blockIdx.x;        // 0..255
  const int bi = b >> 3;            // 0..31: X-row-block (256 rows)
  const int gj = b & 7;             // col-group: col-tile ct = gj*8 + tt

  const int t    = threadIdx.x;
  const int lane = t & 63;
  const int wave = t >> 6;        // 0..7
  const int wm   = wave >> 1;     // 0..3  (64-row band)
  const int wn   = wave & 1;      // 0..1  (64-col half)
  const int quad = lane >> 4;     // 0..3
  const int l15  = lane & 15;

  const unsigned char* Xblk = X + (size_t)(bi * 256) * D_DIM;

  // ---- prologue: stage X (4096 slots of 16B, 8 per thread) ----
#pragma unroll
  for (int it = 0; it < 8; ++it) {
    const int c0  = (it * 8 + wave) * 64;
    const int s   = c0 + lane;
    const int row = s >> 4;                 // 0..255
    const int cg  = (s & 15) ^ (row & 15);  // inverse swizzle on global side
    gl_lds16(Xblk + (size_t)row * D_DIM + cg * 16, &Xs[c0 * 16]);
  }
  // stage Y tile 0 (2048 slots, 4 per thread) into buffer 0
  {
    const unsigned char* Yblk = Y + (size_t)(gj * 8) * 128 * D_DIM;
#pragma unroll
    for (int it = 0; it < 4; ++it) {
      const int c0  = (it * 8 + wave) * 64;
      const int s   = c0 + lane;
      const int row = s >> 4;                 // 0..127
      const int cg  = (s & 15) ^ (row & 15);
      gl_lds16(Yblk + (size_t)row * D_DIM + cg * 16, &Ys[0][c0 * 16]);
    }
  }

  __syncthreads();   // X + Y0 resident (barrier drains vmcnt)

  // ---- load X fragments into registers ONCE (Xs dead afterwards) ----
  i32x8 a8r[2][4];   // [kb][mt], 64 VGPRs
#pragma unroll
  for (int kb = 0; kb < 2; ++kb) {
#pragma unroll
    for (int mt = 0; mt < 4; ++mt) {
      const int row = wm * 64 + mt * 16 + l15;
      const int p0  = (kb * 8 + quad * 2 + 0) ^ (row & 15);
      const int p1  = (kb * 8 + quad * 2 + 1) ^ (row & 15);
      i32x4 lo = *(const i32x4*)(&Xs[row * 256 + p0 * 16]);
      i32x4 hi = *(const i32x4*)(&Xs[row * 256 + p1 * 16]);
      a8r[kb][mt] = __builtin_shufflevector(lo, hi, 0, 1, 2, 3, 4, 5, 6, 7);
    }
  }

  f32x4 acc[4][4];
#pragma unroll
  for (int a = 0; a < 4; ++a)
#pragma unroll
    for (int c = 0; c < 4; ++c) acc[a][c] = (f32x4){0.f, 0.f, 0.f, 0.f};

  float psum[4][4];   // per-lane running row-sum partials (over this lane's cols)
#pragma unroll
  for (int a = 0; a < 4; ++a)
#pragma unroll
    for (int c = 0; c < 4; ++c) psum[a][c] = 0.f;

  for (int tt = 0; tt < 8; ++tt) {
    const int p = tt & 1;

    if (tt) __syncthreads();   // round tt staged (vmcnt drained by barrier)

    if (tt < 7) {      // stage Y tile tt+1 into the other buffer
      const unsigned char* Yblk = Y + (size_t)(gj * 8 + tt + 1) * 128 * D_DIM;
#pragma unroll
      for (int it = 0; it < 4; ++it) {
        const int c0  = (it * 8 + wave) * 64;
        const int s   = c0 + lane;
        const int row = s >> 4;
        const int cg  = (s & 15) ^ (row & 15);
        gl_lds16(Yblk + (size_t)row * D_DIM + cg * 16, &Ys[p ^ 1][c0 * 16]);
      }
    }

    // full-K compute: 2 MX k-blocks of 128; per kb: 8 B-frag b128 reads + 16 MFMA
    // (A fragments already in registers — no per-round A LDS reads)
#pragma unroll
    for (int kb = 0; kb < 2; ++kb) {
      i32x8 b8[4];
#pragma unroll
      for (int nt = 0; nt < 4; ++nt) {
        const int row = wn * 64 + nt * 16 + l15;
        const int p0  = (kb * 8 + quad * 2 + 0) ^ (row & 15);
        const int p1  = (kb * 8 + quad * 2 + 1) ^ (row & 15);
        i32x4 lo = *(const i32x4*)(&Ys[p][row * 256 + p0 * 16]);
        i32x4 hi = *(const i32x4*)(&Ys[p][row * 256 + p1 * 16]);
        b8[nt] = __builtin_shufflevector(lo, hi, 0, 1, 2, 3, 4, 5, 6, 7);
      }
#pragma unroll
      for (int mt = 0; mt < 4; ++mt)
#pragma unroll
        for (int nt = 0; nt < 4; ++nt)
          acc[mt][nt] = __builtin_amdgcn_mfma_scale_f32_16x16x128_f8f6f4(
              a8r[kb][mt], b8[nt], acc[mt][nt],
              0, 0,                    // cbsz=fp8 e4m3, blgp=fp8 e4m3
              0, 0x7F7F7F7F,           // A scales = 1.0 (E8M0 127)
              0, 0x7F7F7F7F);          // B scales = 1.0
    }

    // ---- epilogue: exp + accumulate into REGISTERS (pure VALU, no shfl/LDS) ----
#pragma unroll
    for (int mt = 0; mt < 4; ++mt) {
#pragma unroll
      for (int rr = 0; rr < 4; ++rr) {
        float part = 0.f;
#pragma unroll
        for (int nt = 0; nt < 4; ++nt)
          part += __builtin_amdgcn_exp2f(acc[mt][nt][rr] * kScaleAcc);
        psum[mt][rr] += part;
      }
    }
    // diagonal: col-tile ct overlaps rows iff ct==2*bi (wm==wn) or 2*bi+1
    // (wm==wn+2). Device-scope atomicExch so the finalizer reads coherently.
    {
      const int ct = gj * 8 + tt;
      const bool d0 = (ct == 2 * bi)     && (wm == wn);
      const bool d1 = (ct == 2 * bi + 1) && (wm == wn + 2);
      if (d0 || d1) {
        const int gi_base = bi * 256 + wm * 64;
#pragma unroll
        for (int nt = 0; nt < 4; ++nt)
#pragma unroll
          for (int rr = 0; rr < 4; ++rr)
            if (l15 == quad * 4 + rr)
              atomicExch(&diag[gi_base + nt * 16 + l15], acc[nt][nt][rr]);
      }
    }
#pragma unroll
    for (int a = 0; a < 4; ++a)
#pragma unroll
      for (int c = 0; c < 4; ++c) acc[a][c] = (f32x4){0.f, 0.f, 0.f, 0.f};
  }

  // ---- one reduce + flush per block (16 shfl-chains + 16 atomics per wave) ----
  {
    const int gi_base = bi * 256 + wm * 64;
#pragma unroll
    for (int mt = 0; mt < 4; ++mt) {
#pragma unroll
      for (int rr = 0; rr < 4; ++rr) {
        float v = psum[mt][rr];
        v += __shfl_xor(v, 1);
        v += __shfl_xor(v, 2);
        v += __shfl_xor(v, 4);
        v += __shfl_xor(v, 8);
        if (l15 == 0)
          atomicAdd(&rowsum[gi_base + mt * 16 + quad * 4 + rr], v);
      }
    }
  }

  // ---- per-bi-group finalize: 8th block of group bi handles its 256 rows ----
  __syncthreads();                       // drains this block's atomics (vmcnt)
  if (t == 0) ticket_s = atomicAdd(&done[bi], 1u);
  __syncthreads();
  if (ticket_s == 7u) {
    __threadfence();                     // one acquire, one block per group
    float local = 0.f;
    if (t < 256) {
      const int i = bi * 256 + t;
      const float rs = atomicAdd(&rowsum[i], 0.0f);   // device-coherent read
      const float d  = atomicAdd(&diag[i], 0.0f);
      local = __logf(rs - __builtin_amdgcn_exp2f(d * kScaleAcc)) - d * kInvTAcc;
    }
    local += __shfl_down(local, 32);
    local += __shfl_down(local, 16);
    local += __shfl_down(local, 8);
    local += __shfl_down(local, 4);
    local += __shfl_down(local, 2);
    local += __shfl_down(local, 1);
    float* red = (float*)Xs;             // Xs long dead; reuse as reduce scratch
    if (lane == 0) red[wave] = local;
    __syncthreads();
    if (t == 0) {
      float s = 0.f;
#pragma unroll
      for (int w = 0; w < 8; ++w) s += red[w];
      atomicAdd(out, s / (float)N_ROWS);
    }
  }
}

extern "C" void kernel_launch(void* const* d_in, const int* in_sizes, int n_in,
                              void* d_out, int out_size, void* d_ws, size_t ws_size,
                              hipStream_t stream) {
  const float* x = (const float*)d_in[0];
  const float* y = (const float*)d_in[1];
  float* out = (float*)d_out;

  // ws layout: rowsum[N] f32 | diag[N] f32 | done[32] u32 (128 B) | xq | yq
  float* rowsum = (float*)d_ws;
  float* diag   = rowsum + N_ROWS;
  unsigned int* done = (unsigned int*)(diag + N_ROWS);
  unsigned char* xq = (unsigned char*)d_ws + 2 * N_ROWS * sizeof(float) + 128;
  unsigned char* yq = xq + (size_t)N_ROWS * D_DIM;

  int cvt_blocks = 2 * N_ROWS * D_DIM / 8 / 256;  // 2048
  cvt_fp8_kernel<<<cvt_blocks, 256, 0, stream>>>(x, y, xq, yq, rowsum, done, out);

  infonce_gemm<<<256, 512, 0, stream>>>(xq, yq, rowsum, diag, done, out);
}

// Round 3
// 104.082 us; speedup vs baseline: 1.0088x; 1.0088x over previous
//
#include <hip/hip_runtime.h>
#include <hip/hip_bf16.h>

#define N_ROWS 8192
#define D_DIM  256

// loss_i = log(sum_{j != i} exp(<x_i,y_j>/T)) - <x_i,y_i>/T ; out = mean_i loss_i
// fp8 e4m3 inputs (scale 64), PLAIN row-major; acc = 4096*<x,y> via MX-scaled
// MFMA 16x16x128 with unit E8M0 scales (exact fp8 dot); 1/4096 in constants.
static constexpr float kQuantScale = 64.0f;
static constexpr float kScaleAcc = 20.609929155556627f / 4096.0f;  // (1/T)*log2(e)/4096
static constexpr float kInvTAcc  = 14.285714285714286f / 4096.0f;  // (1/T)/4096

typedef float f32x4 __attribute__((ext_vector_type(4)));
typedef int   i32x4 __attribute__((ext_vector_type(4)));
typedef int   i32x8 __attribute__((ext_vector_type(8)));

// async 16B global->LDS: LDS dest = wave-uniform base + lane*16
__device__ __forceinline__ void gl_lds16(const void* g, void* l) {
  __builtin_amdgcn_global_load_lds(
      (const __attribute__((address_space(1))) void*)g,
      (__attribute__((address_space(3))) void*)l, 16, 0, 0);
}

// ---------------- fp32 -> fp8 e4m3 pre-convert (plain layout) + ws init --------
__global__ __launch_bounds__(256)
void cvt_fp8_kernel(const float* __restrict__ x, const float* __restrict__ y,
                    unsigned char* __restrict__ xq, unsigned char* __restrict__ yq,
                    float* __restrict__ rowsum, unsigned int* __restrict__ done,
                    float* __restrict__ out) {
  if (blockIdx.x == 0) {
    for (int i = threadIdx.x; i < N_ROWS; i += 256) rowsum[i] = 0.f;
    if (threadIdx.x < 32) done[threadIdx.x] = 0u;
    if (threadIdx.x == 32) out[0] = 0.f;
  }
  const int per_mat = N_ROWS * D_DIM / 8;  // 8 elements per thread
  int idx = blockIdx.x * blockDim.x + threadIdx.x;
  const float* src = x;
  unsigned char* dst = xq;
  int i = idx;
  if (idx >= per_mat) { src = y; dst = yq; i = idx - per_mat; }
  float4 a = ((const float4*)src)[2 * (size_t)i];
  float4 b = ((const float4*)src)[2 * (size_t)i + 1];
  int v0 = 0, v1 = 0;
  v0 = __builtin_amdgcn_cvt_pk_fp8_f32(a.x * kQuantScale, a.y * kQuantScale, v0, false);
  v0 = __builtin_amdgcn_cvt_pk_fp8_f32(a.z * kQuantScale, a.w * kQuantScale, v0, true);
  v1 = __builtin_amdgcn_cvt_pk_fp8_f32(b.x * kQuantScale, b.y * kQuantScale, v1, false);
  v1 = __builtin_amdgcn_cvt_pk_fp8_f32(b.z * kQuantScale, b.w * kQuantScale, v1, true);
  *(int2*)(dst + (size_t)i * 8) = make_int2(v0, v1);   // plain row-major
}

// ---------------- persistent fused GEMM(MX-fp8) + exp + row-sum + finalize -----
// R15 chassis: 256 persistent blocks (1/CU), 512 threads = 8 waves (wm 0..3,
// wn 0..1). X-block (256 rows, full K) staged once (64 KB); Y: 8 tiles of 128
// cols full-K double-buffered (64 KB). 8 rounds, one barrier per tile.
// R17: row-sum partials in 16 registers (psum), one reduce+flush per block.
// R18 (a) REVERTED: hoisting A-fragments to registers regressed 45->56 us —
//   compiler placed them in AGPRs (VGPR 120, no spill traffic) and the
//   AGPR->VGPR sourcing serialized with MFMA issue. A stays in LDS.
// R19/R20 CHANGES (R19 never measured — container failure; resubmitted):
//  (a) DEFERRED EPILOGUE: round tt-1's exp2/psum/diag/acc-zero (register-only,
//      ~1k cy of VALU+trans) runs inside round tt, between the kb=0 ds_read
//      issue and the kb=0 MFMAs — i.e. in the shadow of the LDS-read latency
//      instead of serial after the MFMAs before the barrier.
//  (b) finalize distributed per bi-group (kept from R18): the 8 blocks
//      sharing bi ticket on done[bi]; the 8th finalizes its 256 rows and
//      atomicAdds the partial loss into out (zeroed by cvt). 32 concurrent
//      finalizes replace the serial 1-block 8192-row tail.
__global__ __launch_bounds__(512, 1)
void infonce_gemm(const unsigned char* __restrict__ X,
                  const unsigned char* __restrict__ Y,
                  float* __restrict__ rowsum, float* __restrict__ diag,
                  unsigned int* __restrict__ done, float* __restrict__ out) {
  __shared__ unsigned char Xs[256 * 256];      // 64 KB, X-block full-K
  __shared__ unsigned char Ys[2][128 * 256];   // 2 x 32 KB, Y tile dbuf
  __shared__ unsigned int ticket_s;

  const int b  = blockIdx.x;        // 0..255
  const int bi = b >> 3;            // 0..31: X-row-block (256 rows)
  const int gj = b & 7;             // col-group: col-tile ct = gj*8 + tt

  const int t    = threadIdx.x;
  const int lane = t & 63;
  const int wave = t >> 6;        // 0..7
  const int wm   = wave >> 1;     // 0..3  (64-row band)
  const int wn   = wave & 1;      // 0..1  (64-col half)
  const int quad = lane >> 4;     // 0..3
  const int l15  = lane & 15;

  const unsigned char* Xblk = X + (size_t)(bi * 256) * D_DIM;

  // ---- prologue: stage X (4096 slots of 16B, 8 per thread) ----
#pragma unroll
  for (int it = 0; it < 8; ++it) {
    const int c0  = (it * 8 + wave) * 64;
    const int s   = c0 + lane;
    const int row = s >> 4;                 // 0..255
    const int cg  = (s & 15) ^ (row & 15);  // inverse swizzle on global side
    gl_lds16(Xblk + (size_t)row * D_DIM + cg * 16, &Xs[c0 * 16]);
  }
  // stage Y tile 0 (2048 slots, 4 per thread) into buffer 0
  {
    const unsigned char* Yblk = Y + (size_t)(gj * 8) * 128 * D_DIM;
#pragma unroll
    for (int it = 0; it < 4; ++it) {
      const int c0  = (it * 8 + wave) * 64;
      const int s   = c0 + lane;
      const int row = s >> 4;                 // 0..127
      const int cg  = (s & 15) ^ (row & 15);
      gl_lds16(Yblk + (size_t)row * D_DIM + cg * 16, &Ys[0][c0 * 16]);
    }
  }

  f32x4 acc[4][4];
#pragma unroll
  for (int a = 0; a < 4; ++a)
#pragma unroll
    for (int c = 0; c < 4; ++c) acc[a][c] = (f32x4){0.f, 0.f, 0.f, 0.f};

  float psum[4][4];   // per-lane running row-sum partials (over this lane's cols)
#pragma unroll
  for (int a = 0; a < 4; ++a)
#pragma unroll
    for (int c = 0; c < 4; ++c) psum[a][c] = 0.f;

  // deferred epilogue for round rt (acc holds round rt's MFMA results):
  // exp2+psum accumulate, diagonal extraction, acc re-zero. Register-only.
  auto do_epilogue = [&](const int rt) {
#pragma unroll
    for (int mt = 0; mt < 4; ++mt) {
#pragma unroll
      for (int rr = 0; rr < 4; ++rr) {
        float part = 0.f;
#pragma unroll
        for (int nt = 0; nt < 4; ++nt)
          part += __builtin_amdgcn_exp2f(acc[mt][nt][rr] * kScaleAcc);
        psum[mt][rr] += part;
      }
    }
    // diagonal: col-tile ct overlaps rows iff ct==2*bi (wm==wn) or 2*bi+1
    // (wm==wn+2). Device-scope atomicExch so the finalizer reads coherently.
    const int ct = gj * 8 + rt;
    const bool d0 = (ct == 2 * bi)     && (wm == wn);
    const bool d1 = (ct == 2 * bi + 1) && (wm == wn + 2);
    if (d0 || d1) {
      const int gi_base = bi * 256 + wm * 64;
#pragma unroll
      for (int nt = 0; nt < 4; ++nt)
#pragma unroll
        for (int rr = 0; rr < 4; ++rr)
          if (l15 == quad * 4 + rr)
            atomicExch(&diag[gi_base + nt * 16 + l15], acc[nt][nt][rr]);
    }
#pragma unroll
    for (int a = 0; a < 4; ++a)
#pragma unroll
      for (int c = 0; c < 4; ++c) acc[a][c] = (f32x4){0.f, 0.f, 0.f, 0.f};
  };

  for (int tt = 0; tt < 8; ++tt) {
    const int p = tt & 1;

    __syncthreads();   // round tt staged (vmcnt drained by barrier)

    if (tt < 7) {      // stage Y tile tt+1 into the other buffer
      const unsigned char* Yblk = Y + (size_t)(gj * 8 + tt + 1) * 128 * D_DIM;
#pragma unroll
      for (int it = 0; it < 4; ++it) {
        const int c0  = (it * 8 + wave) * 64;
        const int s   = c0 + lane;
        const int row = s >> 4;
        const int cg  = (s & 15) ^ (row & 15);
        gl_lds16(Yblk + (size_t)row * D_DIM + cg * 16, &Ys[p ^ 1][c0 * 16]);
      }
    }

    // full-K compute: 2 MX k-blocks of 128; per kb: 8 frag b128-pairs + 16 MFMA.
    // Round tt-1's epilogue runs between kb=0's load issue and kb=0's MFMAs,
    // hidden under the LDS-read latency.
#pragma unroll
    for (int kb = 0; kb < 2; ++kb) {
      i32x8 a8[4], b8[4];
#pragma unroll
      for (int mt = 0; mt < 4; ++mt) {
        const int row = wm * 64 + mt * 16 + l15;
        const int p0  = (kb * 8 + quad * 2 + 0) ^ (row & 15);
        const int p1  = (kb * 8 + quad * 2 + 1) ^ (row & 15);
        i32x4 lo = *(const i32x4*)(&Xs[row * 256 + p0 * 16]);
        i32x4 hi = *(const i32x4*)(&Xs[row * 256 + p1 * 16]);
        a8[mt] = __builtin_shufflevector(lo, hi, 0, 1, 2, 3, 4, 5, 6, 7);
      }
#pragma unroll
      for (int nt = 0; nt < 4; ++nt) {
        const int row = wn * 64 + nt * 16 + l15;
        const int p0  = (kb * 8 + quad * 2 + 0) ^ (row & 15);
        const int p1  = (kb * 8 + quad * 2 + 1) ^ (row & 15);
        i32x4 lo = *(const i32x4*)(&Ys[p][row * 256 + p0 * 16]);
        i32x4 hi = *(const i32x4*)(&Ys[p][row * 256 + p1 * 16]);
        b8[nt] = __builtin_shufflevector(lo, hi, 0, 1, 2, 3, 4, 5, 6, 7);
      }

      if (kb == 0 && tt > 0) do_epilogue(tt - 1);   // VALU under lgkm shadow

#pragma unroll
      for (int mt = 0; mt < 4; ++mt)
#pragma unroll
        for (int nt = 0; nt < 4; ++nt)
          acc[mt][nt] = __builtin_amdgcn_mfma_scale_f32_16x16x128_f8f6f4(
              a8[mt], b8[nt], acc[mt][nt],
              0, 0,                    // cbsz=fp8 e4m3, blgp=fp8 e4m3
              0, 0x7F7F7F7F,           // A scales = 1.0 (E8M0 127)
              0, 0x7F7F7F7F);          // B scales = 1.0
    }
  }

  do_epilogue(7);   // last round's epilogue (nothing left to overlap with)

  // ---- one reduce + flush per block (16 shfl-chains + 16 atomics per wave) ----
  {
    const int gi_base = bi * 256 + wm * 64;
#pragma unroll
    for (int mt = 0; mt < 4; ++mt) {
#pragma unroll
      for (int rr = 0; rr < 4; ++rr) {
        float v = psum[mt][rr];
        v += __shfl_xor(v, 1);
        v += __shfl_xor(v, 2);
        v += __shfl_xor(v, 4);
        v += __shfl_xor(v, 8);
        if (l15 == 0)
          atomicAdd(&rowsum[gi_base + mt * 16 + quad * 4 + rr], v);
      }
    }
  }

  // ---- per-bi-group finalize: 8th block of group bi handles its 256 rows ----
  __syncthreads();                       // drains this block's atomics (vmcnt)
  if (t == 0) ticket_s = atomicAdd(&done[bi], 1u);
  __syncthreads();
  if (ticket_s == 7u) {
    __threadfence();                     // one acquire, one block per group
    float local = 0.f;
    if (t < 256) {
      const int i = bi * 256 + t;
      const float rs = atomicAdd(&rowsum[i], 0.0f);   // device-coherent read
      const float d  = atomicAdd(&diag[i], 0.0f);
      local = __logf(rs - __builtin_amdgcn_exp2f(d * kScaleAcc)) - d * kInvTAcc;
    }
    local += __shfl_down(local, 32);
    local += __shfl_down(local, 16);
    local += __shfl_down(local, 8);
    local += __shfl_down(local, 4);
    local += __shfl_down(local, 2);
    local += __shfl_down(local, 1);
    float* red = (float*)Xs;             // Xs dead after last round; reuse
    if (lane == 0) red[wave] = local;
    __syncthreads();
    if (t == 0) {
      float s = 0.f;
#pragma unroll
      for (int w = 0; w < 8; ++w) s += red[w];
      atomicAdd(out, s / (float)N_ROWS);
    }
  }
}

extern "C" void kernel_launch(void* const* d_in, const int* in_sizes, int n_in,
                              void* d_out, int out_size, void* d_ws, size_t ws_size,
                              hipStream_t stream) {
  const float* x = (const float*)d_in[0];
  const float* y = (const float*)d_in[1];
  float* out = (float*)d_out;

  // ws layout: rowsum[N] f32 | diag[N] f32 | done[32] u32 (128 B) | xq | yq
  float* rowsum = (float*)d_ws;
  float* diag   = rowsum + N_ROWS;
  unsigned int* done = (unsigned int*)(diag + N_ROWS);
  unsigned char* xq = (unsigned char*)d_ws + 2 * N_ROWS * sizeof(float) + 128;
  unsigned char* yq = xq + (size_t)N_ROWS * D_DIM;

  int cvt_blocks = 2 * N_ROWS * D_DIM / 8 / 256;  // 2048
  cvt_fp8_kernel<<<cvt_blocks, 256, 0, stream>>>(x, y, xq, yq, rowsum, done, out);

  infonce_gemm<<<256, 512, 0, stream>>>(xq, yq, rowsum, diag, done, out);
}

// Round 4
// 101.642 us; speedup vs baseline: 1.0331x; 1.0240x over previous
//
#include <hip/hip_runtime.h>
#include <hip/hip_bf16.h>

#define N_ROWS 8192
#define D_DIM  256

// loss_i = log(sum_{j != i} exp(<x_i,y_j>/T)) - <x_i,y_i>/T ; out = mean_i loss_i
// fp8 e4m3 inputs (scale 64), PLAIN row-major; acc = 4096*<x,y> via MX-scaled
// MFMA 16x16x128 with unit E8M0 scales (exact fp8 dot); 1/4096 in constants.
static constexpr float kQuantScale = 64.0f;
static constexpr float kScaleAcc = 20.609929155556627f / 4096.0f;  // (1/T)*log2(e)/4096
static constexpr float kInvTAcc  = 14.285714285714286f / 4096.0f;  // (1/T)/4096

typedef float f32x4 __attribute__((ext_vector_type(4)));
typedef int   i32x4 __attribute__((ext_vector_type(4)));
typedef int   i32x8 __attribute__((ext_vector_type(8)));

// async 16B global->LDS: LDS dest = wave-uniform base + lane*16
__device__ __forceinline__ void gl_lds16(const void* g, void* l) {
  __builtin_amdgcn_global_load_lds(
      (const __attribute__((address_space(1))) void*)g,
      (__attribute__((address_space(3))) void*)l, 16, 0, 0);
}

// ---------------- fp32 -> fp8 e4m3 pre-convert (plain layout) + ws init --------
__global__ __launch_bounds__(256)
void cvt_fp8_kernel(const float* __restrict__ x, const float* __restrict__ y,
                    unsigned char* __restrict__ xq, unsigned char* __restrict__ yq,
                    float* __restrict__ rowsum, unsigned int* __restrict__ done,
                    float* __restrict__ out) {
  if (blockIdx.x == 0) {
    for (int i = threadIdx.x; i < N_ROWS; i += 256) rowsum[i] = 0.f;
    if (threadIdx.x < 32) done[threadIdx.x] = 0u;
    if (threadIdx.x == 32) out[0] = 0.f;
  }
  const int per_mat = N_ROWS * D_DIM / 8;  // 8 elements per thread
  int idx = blockIdx.x * blockDim.x + threadIdx.x;
  const float* src = x;
  unsigned char* dst = xq;
  int i = idx;
  if (idx >= per_mat) { src = y; dst = yq; i = idx - per_mat; }
  float4 a = ((const float4*)src)[2 * (size_t)i];
  float4 b = ((const float4*)src)[2 * (size_t)i + 1];
  int v0 = 0, v1 = 0;
  v0 = __builtin_amdgcn_cvt_pk_fp8_f32(a.x * kQuantScale, a.y * kQuantScale, v0, false);
  v0 = __builtin_amdgcn_cvt_pk_fp8_f32(a.z * kQuantScale, a.w * kQuantScale, v0, true);
  v1 = __builtin_amdgcn_cvt_pk_fp8_f32(b.x * kQuantScale, b.y * kQuantScale, v1, false);
  v1 = __builtin_amdgcn_cvt_pk_fp8_f32(b.z * kQuantScale, b.w * kQuantScale, v1, true);
  *(int2*)(dst + (size_t)i * 8) = make_int2(v0, v1);   // plain row-major
}

// ---------------- persistent fused GEMM(MX-fp8) + exp + row-sum + finalize -----
// R21 REDESIGN: 2 blocks/CU (was 1). R17's counters (MfmaUtil 13, VALUBusy 19,
// Occ 14, HBM 3%, conflicts 0) say latency-bound: the single 8-wave block
// convoys on one barrier per round with nothing else on the CU to fill the
// MFMA/VALU pipes during lgkm/vmcnt stalls. R18/R19 micro-scheduling inside
// the block both regressed (compiler already schedules the round body well).
// New geometry: 512 blocks x 512 thr; block = 128 rows x 1024 cols.
//   LDS: Xs 32 KB + Ys 2x16 KB = 64 KB -> 2 blocks/CU (16 waves, 4/SIMD).
//   __launch_bounds__(512,4) caps VGPR at 128 (acc now 2x2 frags = 16 regs).
//   16 rounds of 64 Y-cols, dbuf, one barrier per round; two independent
//   barrier domains per CU overlap each other's stalls.
//   Wave tile 32x32 (wm 0..3 = 32-row band, wn 0..1 = 32-col half):
//   LDS-read floor ~6.8 us/CU vs MFMA floor 7.4 us -> balanced.
//   Block->XCD: b%8 == gj, so each XCD owns one col-group: Y tiles + its
//   blocks' X panels (2 MB) are XCD-L2-resident.
// Epilogue in-round after MFMAs (R17 style, NOT deferred). Single-ticket
// last-block finalize (R15-proven pattern, ticket==511).
__global__ __launch_bounds__(512, 4)
void infonce_gemm(const unsigned char* __restrict__ X,
                  const unsigned char* __restrict__ Y,
                  float* __restrict__ rowsum, float* __restrict__ diag,
                  unsigned int* __restrict__ done, float* __restrict__ out) {
  __shared__ unsigned char Xs[128 * 256];      // 32 KB, X-block full-K
  __shared__ unsigned char Ys[2][64 * 256];    // 2 x 16 KB, Y tile dbuf
  __shared__ unsigned int ticket_s;

  const int b  = blockIdx.x;        // 0..511
  const int bi = b >> 3;            // 0..63: X-row-block (128 rows)
  const int gj = b & 7;             // col-group: 1024 Y rows, 16 tiles of 64

  const int t    = threadIdx.x;
  const int lane = t & 63;
  const int wave = t >> 6;        // 0..7
  const int wm   = wave >> 1;     // 0..3  (32-row band)
  const int wn   = wave & 1;      // 0..1  (32-col half)
  const int quad = lane >> 4;     // 0..3
  const int l15  = lane & 15;

  const unsigned char* Xblk = X + (size_t)(bi * 128) * D_DIM;

  // ---- prologue: stage X (2048 slots of 16B, 4 per thread) ----
#pragma unroll
  for (int it = 0; it < 4; ++it) {
    const int c0  = (it * 8 + wave) * 64;
    const int s   = c0 + lane;
    const int row = s >> 4;                 // 0..127
    const int cg  = (s & 15) ^ (row & 15);  // inverse swizzle on global side
    gl_lds16(Xblk + (size_t)row * D_DIM + cg * 16, &Xs[c0 * 16]);
  }
  // stage Y tile 0 (1024 slots, 2 per thread) into buffer 0
  {
    const unsigned char* Yblk = Y + (size_t)(gj * 1024) * D_DIM;
#pragma unroll
    for (int it = 0; it < 2; ++it) {
      const int c0  = (it * 8 + wave) * 64;
      const int s   = c0 + lane;
      const int row = s >> 4;                 // 0..63
      const int cg  = (s & 15) ^ (row & 15);
      gl_lds16(Yblk + (size_t)row * D_DIM + cg * 16, &Ys[0][c0 * 16]);
    }
  }

  f32x4 acc[2][2];
#pragma unroll
  for (int a = 0; a < 2; ++a)
#pragma unroll
    for (int c = 0; c < 2; ++c) acc[a][c] = (f32x4){0.f, 0.f, 0.f, 0.f};

  float psum[2][4];   // per-lane running row-sum partials (frag-row mt, reg rr)
#pragma unroll
  for (int a = 0; a < 2; ++a)
#pragma unroll
    for (int c = 0; c < 4; ++c) psum[a][c] = 0.f;

  // diagonal rounds: global row r == global col c requires
  // bi*128 + lrow == gj*1024 + tt*64 + lcol with lrow in [0,128);
  // gj == bi>>3 implied, tt = (bi&7)*2 + h, h in {0,1}, lrow = 64h + lcol.
  // At wave level (lrow = wm*32+mt*16+quad*4+rr, lcol = wn*32+nt*16+l15):
  // h==0 -> wm==wn; h==1 -> wm==wn+2; then mt==nt and l15==quad*4+rr.
  const int tbase = (bi & 7) * 2;

  for (int tt = 0; tt < 16; ++tt) {
    const int p = tt & 1;

    __syncthreads();   // round tt staged (vmcnt drained by barrier)

    if (tt < 15) {     // stage Y tile tt+1 into the other buffer
      const unsigned char* Yblk = Y + (size_t)(gj * 1024 + (tt + 1) * 64) * D_DIM;
#pragma unroll
      for (int it = 0; it < 2; ++it) {
        const int c0  = (it * 8 + wave) * 64;
        const int s   = c0 + lane;
        const int row = s >> 4;
        const int cg  = (s & 15) ^ (row & 15);
        gl_lds16(Yblk + (size_t)row * D_DIM + cg * 16, &Ys[p ^ 1][c0 * 16]);
      }
    }

    // full-K compute: 2 MX k-blocks of 128; per kb: 4 frag b128-pairs + 4 MFMA
#pragma unroll
    for (int kb = 0; kb < 2; ++kb) {
      i32x8 a8[2], b8[2];
#pragma unroll
      for (int mt = 0; mt < 2; ++mt) {
        const int row = wm * 32 + mt * 16 + l15;
        const int p0  = (kb * 8 + quad * 2 + 0) ^ (row & 15);
        const int p1  = (kb * 8 + quad * 2 + 1) ^ (row & 15);
        i32x4 lo = *(const i32x4*)(&Xs[row * 256 + p0 * 16]);
        i32x4 hi = *(const i32x4*)(&Xs[row * 256 + p1 * 16]);
        a8[mt] = __builtin_shufflevector(lo, hi, 0, 1, 2, 3, 4, 5, 6, 7);
      }
#pragma unroll
      for (int nt = 0; nt < 2; ++nt) {
        const int row = wn * 32 + nt * 16 + l15;
        const int p0  = (kb * 8 + quad * 2 + 0) ^ (row & 15);
        const int p1  = (kb * 8 + quad * 2 + 1) ^ (row & 15);
        i32x4 lo = *(const i32x4*)(&Ys[p][row * 256 + p0 * 16]);
        i32x4 hi = *(const i32x4*)(&Ys[p][row * 256 + p1 * 16]);
        b8[nt] = __builtin_shufflevector(lo, hi, 0, 1, 2, 3, 4, 5, 6, 7);
      }
#pragma unroll
      for (int mt = 0; mt < 2; ++mt)
#pragma unroll
        for (int nt = 0; nt < 2; ++nt)
          acc[mt][nt] = __builtin_amdgcn_mfma_scale_f32_16x16x128_f8f6f4(
              a8[mt], b8[nt], acc[mt][nt],
              0, 0,                    // cbsz=fp8 e4m3, blgp=fp8 e4m3
              0, 0x7F7F7F7F,           // A scales = 1.0 (E8M0 127)
              0, 0x7F7F7F7F);          // B scales = 1.0
    }

    // ---- epilogue (in-round, R17 style): exp + accumulate into registers ----
#pragma unroll
    for (int mt = 0; mt < 2; ++mt) {
#pragma unroll
      for (int rr = 0; rr < 4; ++rr) {
        float part = 0.f;
#pragma unroll
        for (int nt = 0; nt < 2; ++nt)
          part += __builtin_amdgcn_exp2f(acc[mt][nt][rr] * kScaleAcc);
        psum[mt][rr] += part;
      }
    }
    // diagonal extraction (device-scope atomicExch; finalizer reads coherently)
    {
      const int h = tt - tbase;
      const bool d0 = (h == 0) && (wm == wn);
      const bool d1 = (h == 1) && (wm == wn + 2);
      if (d0 || d1) {
        const int gi_base = bi * 128 + wm * 32;
#pragma unroll
        for (int nt = 0; nt < 2; ++nt)
#pragma unroll
          for (int rr = 0; rr < 4; ++rr)
            if (l15 == quad * 4 + rr)
              atomicExch(&diag[gi_base + nt * 16 + l15], acc[nt][nt][rr]);
      }
    }
#pragma unroll
    for (int a = 0; a < 2; ++a)
#pragma unroll
      for (int c = 0; c < 2; ++c) acc[a][c] = (f32x4){0.f, 0.f, 0.f, 0.f};
  }

  // ---- one reduce + flush per block (8 shfl-chains + 8 atomics per wave) ----
  {
    const int gi_base = bi * 128 + wm * 32;
#pragma unroll
    for (int mt = 0; mt < 2; ++mt) {
#pragma unroll
      for (int rr = 0; rr < 4; ++rr) {
        float v = psum[mt][rr];
        v += __shfl_xor(v, 1);
        v += __shfl_xor(v, 2);
        v += __shfl_xor(v, 4);
        v += __shfl_xor(v, 8);
        if (l15 == 0)
          atomicAdd(&rowsum[gi_base + mt * 16 + quad * 4 + rr], v);
      }
    }
  }

  // ---- last-block finalize (single fence, single ticket — R15-proven) ----
  __syncthreads();                       // drains this block's atomics (vmcnt)
  if (t == 0) ticket_s = atomicAdd(&done[0], 1u);
  __syncthreads();
  if (ticket_s == 511u) {
    __threadfence();                     // one acquire, one block only
    float local = 0.f;
    for (int i = t; i < N_ROWS; i += 512) {
      const float rs = atomicAdd(&rowsum[i], 0.0f);   // device-coherent read
      const float d  = atomicAdd(&diag[i], 0.0f);
      local += __logf(rs - __builtin_amdgcn_exp2f(d * kScaleAcc)) - d * kInvTAcc;
    }
    float* red = (float*)Xs;             // Xs dead after last round; reuse
    red[t] = local;
    __syncthreads();
    for (int s2 = 256; s2 > 0; s2 >>= 1) {
      if (t < s2) red[t] += red[t + s2];
      __syncthreads();
    }
    if (t == 0) out[0] = red[0] / (float)N_ROWS;
  }
}

extern "C" void kernel_launch(void* const* d_in, const int* in_sizes, int n_in,
                              void* d_out, int out_size, void* d_ws, size_t ws_size,
                              hipStream_t stream) {
  const float* x = (const float*)d_in[0];
  const float* y = (const float*)d_in[1];
  float* out = (float*)d_out;

  // ws layout: rowsum[N] f32 | diag[N] f32 | done[32] u32 (128 B) | xq | yq
  float* rowsum = (float*)d_ws;
  float* diag   = rowsum + N_ROWS;
  unsigned int* done = (unsigned int*)(diag + N_ROWS);
  unsigned char* xq = (unsigned char*)d_ws + 2 * N_ROWS * sizeof(float) + 128;
  unsigned char* yq = xq + (size_t)N_ROWS * D_DIM;

  int cvt_blocks = 2 * N_ROWS * D_DIM / 8 / 256;  // 2048
  cvt_fp8_kernel<<<cvt_blocks, 256, 0, stream>>>(x, y, xq, yq, rowsum, done, out);

  infonce_gemm<<<512, 512, 0, stream>>>(xq, yq, rowsum, diag, done, out);
}